// Round 14
// baseline (158.828 us; speedup 1.0000x reference)
//
#include <hip/hip_runtime.h>
#include <stdint.h>

// Problem constants (fixed by the reference)
#define BB   2
#define SS   2048
#define DD   768
#define HH   12
#define MM   (BB*SS)          // 4096 rows in all GEMMs
#define XSZ  (MM*DD)          // 3,145,728
#define WSZ  (DD*DD)          //   589,824

typedef __bf16 v8bf __attribute__((ext_vector_type(8)));   // 8 bf16 = 4 VGPRs (MFMA A/B frag)
typedef float  v4f  __attribute__((ext_vector_type(4)));   // MFMA C/D frag (16x16)

__device__ inline v4f mfma16(v8bf a, v8bf b, v4f c) {
    return __builtin_amdgcn_mfma_f32_16x16x32_bf16(a, b, c, 0, 0, 0);
}

// float -> bf16 bits, round-to-nearest-even
__device__ inline unsigned short f2bf(float f) {
    union { float f; uint32_t u; } v; v.f = f;
    return (unsigned short)((v.u + 0x7FFFu + ((v.u >> 16) & 1u)) >> 16);
}

// 8 contiguous fp32 -> 8 bf16 packed into 16 bytes (VGPR staging path)
__device__ inline uint4 cvt8(const float* __restrict__ p) {
    uint4 out;
    unsigned short* s = (unsigned short*)&out;
#pragma unroll
    for (int j = 0; j < 8; ++j) s[j] = f2bf(p[j]);
    return out;
}

// Async 16B global->LDS copy (gfx950). LDS dest is wave-uniform base + lane*16B.
__device__ __forceinline__ void gld_lds16(const unsigned short* g, unsigned short* l) {
    __builtin_amdgcn_global_load_lds(
        (const __attribute__((address_space(1))) void*)g,
        (__attribute__((address_space(3))) void*)l, 16, 0, 0);
}

// ---------------------------------------------------------------------------
// R16-verified: fp32 -> bf16 for Wq,Wk,Wv into d_out's second half (3*WSZ
// elems = 1728 blocks x 256 thr x 4 elems exactly). ~10.6MB => ~2.5us.
// ---------------------------------------------------------------------------
__global__ __launch_bounds__(256) void cvt_w3(
    const float* __restrict__ Wq, const float* __restrict__ Wk,
    const float* __restrict__ Wv, unsigned short* __restrict__ dst)
{
    long i4 = ((long)blockIdx.x * 256 + threadIdx.x) * 4;
    int t = (int)(i4 / WSZ);
    long off = i4 - (long)t * WSZ;
    const float* s = (t == 0) ? Wq : (t == 1) ? Wk : Wv;
    float4 v = *(const float4*)(s + off);
    ushort4 o;
    o.x = f2bf(v.x); o.y = f2bf(v.y); o.z = f2bf(v.z); o.w = f2bf(v.w);
    *(ushort4*)(dst + (size_t)t * WSZ + off) = o;
}

// ---------------------------------------------------------------------------
// R26-verified QKV (R16 structure, B-issues first): X-tile staged once (cvt8,
// XOR-swizzled ds_write), 3 bf16 weight tiles async via global_load_lds
// (source pre-swizzled). 24 MFMA/wave per BK=64 step. Grid (12,64)=768 =
// 3/CU, XCD-chunked.
// ---------------------------------------------------------------------------
__global__ __launch_bounds__(256) void gemm_qkv64(
    const float* __restrict__ X,
    const unsigned short* __restrict__ Wq,
    const unsigned short* __restrict__ Wk,
    const unsigned short* __restrict__ Wv,
    unsigned short* __restrict__ Qo,
    unsigned short* __restrict__ Ko,
    unsigned short* __restrict__ Vo)
{
    __shared__ __align__(16) unsigned short As[64 * 64];
    __shared__ __align__(16) unsigned short Bs[3][64 * 64];

    const int flat = (int)(blockIdx.y * gridDim.x + blockIdx.x);
    const int sw   = (flat & 7) * 96 + (flat >> 3);
    const int m0   = (sw / 12) * 64;
    const int n0   = (sw % 12) * 64;

    const int tid  = threadIdx.x;
    const int wave = tid >> 6, lane = tid & 63;
    const int quad = lane >> 4, l16 = lane & 15;
    const int waveM = (wave >> 1) * 32, waveN = (wave & 1) * 32;

    const int rA  = tid >> 2;
    const int cA  = (tid & 3) * 16;
    const int rxA = (rA & 7) << 4;

    const int rB  = wave * 8 + (lane >> 3);
    const int cB  = ((lane & 7) ^ (lane >> 3)) * 8;
    const int swz = (l16 & 7) << 4;

    v4f acc[3][2][2] = {};

    const float* ap0 = X + (size_t)(m0 + rA) * DD + cA;
    const unsigned short* w0 = Wq + (size_t)(n0 + rB) * DD + cB;
    const unsigned short* w1 = Wk + (size_t)(n0 + rB) * DD + cB;
    const unsigned short* w2 = Wv + (size_t)(n0 + rB) * DD + cB;

    for (int kt = 0; kt < DD; kt += 64) {
        __syncthreads();
        // B first: 6 async issues fly while the A chain stalls on its loads.
        gld_lds16(w0 + kt,           &Bs[0][wave * 512]);
        gld_lds16(w0 + kt + 32 * DD, &Bs[0][2048 + wave * 512]);
        gld_lds16(w1 + kt,           &Bs[1][wave * 512]);
        gld_lds16(w1 + kt + 32 * DD, &Bs[1][2048 + wave * 512]);
        gld_lds16(w2 + kt,           &Bs[2][wave * 512]);
        gld_lds16(w2 + kt + 32 * DD, &Bs[2][2048 + wave * 512]);
        // A: 16 fp32 -> bf16, two swizzled ds_write_b128
        *(uint4*)((char*)As + rA * 128 + ((cA * 2)      ^ rxA)) = cvt8(ap0 + kt);
        *(uint4*)((char*)As + rA * 128 + ((cA * 2 + 16) ^ rxA)) = cvt8(ap0 + kt + 8);
        __syncthreads();

        v8bf af[2][2];
#pragma unroll
        for (int mi = 0; mi < 2; ++mi) {
            const char* arow = (const char*)As + (size_t)(waveM + mi * 16 + l16) * 128;
#pragma unroll
            for (int kf = 0; kf < 2; ++kf)
                af[mi][kf] = *(const v8bf*)(arow + ((kf * 64 + quad * 16) ^ swz));
        }
#pragma unroll
        for (int z = 0; z < 3; ++z) {
            v8bf bfr[2][2];
#pragma unroll
            for (int ni = 0; ni < 2; ++ni) {
                const char* brow = (const char*)&Bs[z][0] + (size_t)(waveN + ni * 16 + l16) * 128;
#pragma unroll
                for (int kf = 0; kf < 2; ++kf)
                    bfr[ni][kf] = *(const v8bf*)(brow + ((kf * 64 + quad * 16) ^ swz));
            }
#pragma unroll
            for (int mi = 0; mi < 2; ++mi)
#pragma unroll
                for (int ni = 0; ni < 2; ++ni) {
                    acc[z][mi][ni] = mfma16(af[mi][0], bfr[ni][0], acc[z][mi][ni]);
                    acc[z][mi][ni] = mfma16(af[mi][1], bfr[ni][1], acc[z][mi][ni]);
                }
        }
    }

    // Epilogue: C/D layout col=l16, row=quad*4+r (verified formula).
#pragma unroll
    for (int mi = 0; mi < 2; ++mi)
#pragma unroll
        for (int ni = 0; ni < 2; ++ni)
#pragma unroll
            for (int r = 0; r < 4; ++r) {
                const int row = m0 + waveM + mi * 16 + quad * 4 + r;
                const int col = n0 + waveN + ni * 16 + l16;
                Qo[(size_t)row * DD + col] = f2bf(acc[0][mi][ni][r]);
                Ko[(size_t)row * DD + col] = f2bf(acc[1][mi][ni][r]);
                const int b = row >> 11, s = row & 2047;
                const int h = col >> 6,  dk = col & 63;
                Vo[(((size_t)(b * HH + h)) * 64 + dk) * SS + s] = f2bf(acc[2][mi][ni][r]);
            }
}

// ---------------------------------------------------------------------------
// R21-verified out-projection: 64x64, BK=64, double-buffered T3 2-phase.
// A bf16 async; W = Wo fp32 via cvt8 swizzled ds_write. Grid (12,64)=768.
// ---------------------------------------------------------------------------
__global__ __launch_bounds__(256) void gemm_of(
    const unsigned short* __restrict__ A,
    const float* __restrict__ W,
    float* __restrict__ C)
{
    __shared__ __align__(16) unsigned short As[2][64 * 64];
    __shared__ __align__(16) unsigned short Bs[2][64 * 64];

    const int flat = (int)(blockIdx.y * gridDim.x + blockIdx.x);  // gx=12
    const int sw   = (flat & 7) * 96 + (flat >> 3);
    const int m0   = (sw / 12) * 64;
    const int n0   = (sw % 12) * 64;

    const int tid  = threadIdx.x;
    const int wave = tid >> 6, lane = tid & 63;
    const int quad = lane >> 4, l16 = lane & 15;
    const int waveM = (wave >> 1) * 32, waveN = (wave & 1) * 32;

    const int rB  = wave * 8 + (lane >> 3);
    const int cB  = ((lane & 7) ^ (lane >> 3)) * 8;
    const int rW  = tid >> 2;
    const int cW  = (tid & 3) * 16;
    const int rxW = (rW & 7) << 4;
    const int swz = (l16 & 7) << 4;

    const unsigned short* a0 = A + (size_t)(m0 + rB) * DD + cB;
    const float*          b0 = W + (size_t)(n0 + rW) * DD + cW;

    v4f acc[2][2] = {};

    gld_lds16(a0,           &As[0][wave * 512]);
    gld_lds16(a0 + 32 * DD, &As[0][2048 + wave * 512]);
    *(uint4*)((char*)&Bs[0][0] + rW * 128 + ((cW * 2)      ^ rxW)) = cvt8(b0);
    *(uint4*)((char*)&Bs[0][0] + rW * 128 + ((cW * 2 + 16) ^ rxW)) = cvt8(b0 + 8);
    __syncthreads();

    int cur = 0;
    for (int kt = 0; kt < DD; kt += 64) {
        if (kt + 64 < DD) {
            gld_lds16(a0 + kt + 64,           &As[cur ^ 1][wave * 512]);
            gld_lds16(a0 + kt + 64 + 32 * DD, &As[cur ^ 1][2048 + wave * 512]);
            *(uint4*)((char*)&Bs[cur ^ 1][0] + rW * 128 + ((cW * 2)      ^ rxW)) = cvt8(b0 + kt + 64);
            *(uint4*)((char*)&Bs[cur ^ 1][0] + rW * 128 + ((cW * 2 + 16) ^ rxW)) = cvt8(b0 + kt + 64 + 8);
        }
#pragma unroll
        for (int kf = 0; kf < 2; ++kf) {
            v8bf af[2], bfr[2];
#pragma unroll
            for (int i = 0; i < 2; ++i) {
                af[i]  = *(const v8bf*)((const char*)&As[cur][0] +
                          (size_t)(waveM + i * 16 + l16) * 128 + ((kf * 64 + quad * 16) ^ swz));
                bfr[i] = *(const v8bf*)((const char*)&Bs[cur][0] +
                          (size_t)(waveN + i * 16 + l16) * 128 + ((kf * 64 + quad * 16) ^ swz));
            }
#pragma unroll
            for (int mi = 0; mi < 2; ++mi)
#pragma unroll
                for (int ni = 0; ni < 2; ++ni)
                    acc[mi][ni] = mfma16(af[mi], bfr[ni], acc[mi][ni]);
        }
        __syncthreads();
        cur ^= 1;
    }

#pragma unroll
    for (int mi = 0; mi < 2; ++mi)
#pragma unroll
        for (int ni = 0; ni < 2; ++ni)
#pragma unroll
            for (int r = 0; r < 4; ++r) {
                const int row = m0 + waveM + mi * 16 + quad * 4 + r;
                const int col = n0 + waveN + ni * 16 + l16;
                C[(size_t)row * DD + col] = acc[mi][ni][r];
            }
}

// ---------------------------------------------------------------------------
// R28 attention: R27 (swapped-QK^T, verified) + T15 one-tile-lagged PV.
// Why: 50688 wave-tiles x ~520cy = measured 43us => per-tile serial chain
// runs with overlap factor ~1. PV(kt-1) depends only on carried P-frags +
// V(kt-1); softmax(kt) depends only on QK(kt) -- deferring PV by one tile
// makes PV-MFMA and softmax-VALU independent within one scheduling region,
// so the two pipes interleave (learn_hip T15: +7-11% attn).
// Plumbing: V triple-buffered ((kt+1)%3 stage vs (kt-1)%3 read never
// collide; end-of-iter barrier orders overwrite), K double-buffered
// (unchanged), P-frags carried in 8 VGPRs (read right after write, as
// before -> Ps needs no dbuf). Epilogue runs PV(NT-1). oacc accumulation
// stays tile-ascending -> bitwise-identical output. LDS 49KB (3 blocks/CU).
// ---------------------------------------------------------------------------
__global__ __launch_bounds__(256, 3) void attn_ls(
    const unsigned short* Q,                 // (B,S,D) bf16 (aliases O)
    const unsigned short* __restrict__ Kg,   // (B,S,D) bf16
    const unsigned short* __restrict__ Vt,   // (B,H,64,S) bf16 transposed
    unsigned short* O)                       // (B,S,D) bf16
{
    const int h = blockIdx.x, b = blockIdx.y;
    const int qs = (SS / 64 - 1 - (int)blockIdx.z) * 64;   // LPT: heavy first
    const int tid  = threadIdx.x;
    const int wave = tid >> 6, lane = tid & 63;
    const int quad = lane >> 4, l16 = lane & 15;
    const int qw = qs + wave * 16;           // this wave's private q rows
    const float scale = 0.125f;              // 1/sqrt(64)

    __shared__ __align__(16) unsigned short Ks[2][4096];   // 2 x 64x64 bf16, swizzled
    __shared__ __align__(16) unsigned short Vs[3][4096];   // 3 x 64x64 bf16, swizzled
    __shared__ __align__(16) unsigned short Ps[4][16 * 72];// per-wave P buffer

    // Q frags for this wave's 16 rows (read before any O write: in-place safe)
    v8bf qf0, qf1;
    {
        const unsigned short* qp = &Q[((size_t)(b * SS + qw + l16)) * DD + h * 64];
        qf0 = *(const v8bf*)(qp + quad * 8);
        qf1 = *(const v8bf*)(qp + 32 + quad * 8);
    }

    const int NT = qs / 64 + 1;              // causal k-tiles, SAME for all 4 waves
    const char* kgb = (const char*)&Kg[(size_t)(b * SS) * DD + h * 64];
    const char* vgb = (const char*)&Vt[((size_t)(b * HH + h) * 64) * SS];

    const int rA = wave * 8 + (lane >> 3);               // rows rA and rA+32
    const int oA = ((lane & 7) * 16) ^ ((rA & 7) << 4);  // swizzled in-row byte
    const int swz = (l16 & 7) << 4;                      // read-side XOR

    v4f oacc[4] = {};
    float l_sum = 0.0f;                      // q-row l16, this quad's partial
    unsigned short* pw = &Ps[wave][0];
    const int qrow = qw + l16;               // lane-uniform mask row

    v8bf paP0, paP1;                         // carried P frags (prev tile)

    // Prologue: stage tile 0 into K buf 0 / V buf 0
    gld_lds16((const unsigned short*)(kgb + (size_t)rA        * (DD * 2) + oA), &Ks[0][wave * 512]);
    gld_lds16((const unsigned short*)(kgb + (size_t)(rA + 32) * (DD * 2) + oA), &Ks[0][2048 + wave * 512]);
    gld_lds16((const unsigned short*)(vgb + (size_t)rA        * (SS * 2) + oA), &Vs[0][wave * 512]);
    gld_lds16((const unsigned short*)(vgb + (size_t)(rA + 32) * (SS * 2) + oA), &Vs[0][2048 + wave * 512]);
    __syncthreads();   // drains vmcnt: tile 0 resident

    for (int kt = 0; kt < NT; ++kt) {
        const int kcur = kt & 1;
        const int kb   = kt * 64;

        // Async-stage NEXT tile: K into the other K-buf, V into (kt+1)%3.
        if (kt + 1 < NT) {
            const size_t kb2 = (size_t)(kb + 64);
            unsigned short* vdst = &Vs[(kt + 1) % 3][0];
            gld_lds16((const unsigned short*)(kgb + (kb2 + rA)      * (DD * 2) + oA), &Ks[kcur ^ 1][wave * 512]);
            gld_lds16((const unsigned short*)(kgb + (kb2 + rA + 32) * (DD * 2) + oA), &Ks[kcur ^ 1][2048 + wave * 512]);
            gld_lds16((const unsigned short*)(vgb + (size_t)rA        * (SS * 2) + kb2 * 2 + oA), vdst + wave * 512);
            gld_lds16((const unsigned short*)(vgb + (size_t)(rA + 32) * (SS * 2) + kb2 * 2 + oA), vdst + 2048 + wave * 512);
        }

        const char* ksb = (const char*)&Ks[kcur][0];

        // K frags from swizzled LDS: row = nk*16+l16, cols half*32 + quad*8..
        v8bf kf0[4], kf1[4];
#pragma unroll
        for (int nk = 0; nk < 4; ++nk) {
            const char* krow = ksb + (size_t)(nk * 16 + l16) * 128;
            kf0[nk] = *(const v8bf*)(krow + ((quad * 16) ^ swz));
            kf1[nk] = *(const v8bf*)(krow + ((64 + quad * 16) ^ swz));
        }

        // S^T = K Q^T (swapped operands): lane = q-row l16; rows = keys.
        v4f sacc[4] = {};
#pragma unroll
        for (int nk = 0; nk < 4; ++nk) {
            sacc[nk] = mfma16(kf0[nk], qf0, sacc[nk]);
            sacc[nk] = mfma16(kf1[nk], qf1, sacc[nk]);
        }

        // PV of the PREVIOUS tile: independent of this tile's softmax, so
        // its 8 MFMAs interleave with the 16 exps below (the T15 dep-break).
        if (kt > 0) {
            const char* vsb = (const char*)&Vs[(kt + 2) % 3][0];   // == (kt-1)%3
            v8bf vf[2][4];
#pragma unroll
            for (int kc = 0; kc < 2; ++kc)
#pragma unroll
                for (int dt = 0; dt < 4; ++dt) {
                    const char* vr = vsb + (size_t)(dt * 16 + l16) * 128;
                    vf[kc][dt] = *(const v8bf*)(vr + ((kc * 64 + quad * 16) ^ swz));
                }
#pragma unroll
            for (int dt = 0; dt < 4; ++dt) oacc[dt] = mfma16(paP0, vf[0][dt], oacc[dt]);
#pragma unroll
            for (int dt = 0; dt < 4; ++dt) oacc[dt] = mfma16(paP1, vf[1][dt], oacc[dt]);
        }

        // fixed-base softmax: p = exp(s/8); mask only on the diagonal tile.
        const bool diag = (kt == NT - 1);
        float pv[4][4];
#pragma unroll
        for (int nk = 0; nk < 4; ++nk)
#pragma unroll
            for (int r = 0; r < 4; ++r) {
                float p = __expf(sacc[nk][r] * scale);
                if (diag) {
                    int key = kb + nk * 16 + quad * 4 + r;
                    if (key > qrow) p = 0.0f;
                }
                pv[nk][r] = p;
                l_sum += p;
            }

        // P chunks -> per-wave LDS [qrow][key] (stride 72): 4 x ds_write_b64,
        // then read back the A-frags and CARRY them to the next iteration.
#pragma unroll
        for (int nk = 0; nk < 4; ++nk) {
            uint2 c;
            c.x = (uint32_t)f2bf(pv[nk][0]) | ((uint32_t)f2bf(pv[nk][1]) << 16);
            c.y = (uint32_t)f2bf(pv[nk][2]) | ((uint32_t)f2bf(pv[nk][3]) << 16);
            *(uint2*)(&pw[l16 * 72 + nk * 16 + quad * 4]) = c;
        }
        __asm__ volatile("" ::: "memory");

        paP0 = *(const v8bf*)(&pw[l16 * 72 + quad * 8]);
        paP1 = *(const v8bf*)(&pw[l16 * 72 + 32 + quad * 8]);

        // One barrier per tile: K/V reads of this tile done (so next iter may
        // restage those buffers) + next tile's staging resident.
        __syncthreads();
    }

    // Epilogue: PV of the last tile (its V buffer is no longer restaged).
    {
        const char* vsb = (const char*)&Vs[(NT + 2) % 3][0];   // == (NT-1)%3
        v8bf vf[2][4];
#pragma unroll
        for (int kc = 0; kc < 2; ++kc)
#pragma unroll
            for (int dt = 0; dt < 4; ++dt) {
                const char* vr = vsb + (size_t)(dt * 16 + l16) * 128;
                vf[kc][dt] = *(const v8bf*)(vr + ((kc * 64 + quad * 16) ^ swz));
            }
#pragma unroll
        for (int dt = 0; dt < 4; ++dt) oacc[dt] = mfma16(paP0, vf[0][dt], oacc[dt]);
#pragma unroll
        for (int dt = 0; dt < 4; ++dt) oacc[dt] = mfma16(paP1, vf[1][dt], oacc[dt]);
    }

    // l_sum is the quad-partial for q-row l16: reduce across the 4 quads,
    // then broadcast the sums this lane's 4 output rows need.
    l_sum += __shfl_xor(l_sum, 16, 64);
    l_sum += __shfl_xor(l_sum, 32, 64);
    float inv[4];
#pragma unroll
    for (int r = 0; r < 4; ++r)
        inv[r] = 1.0f / __shfl(l_sum, quad * 4 + r, 64);

    // Direct per-wave store: lane holds O[qw+quad*4+r][dt*16+l16] (C layout).
    unsigned short* ob = &O[((size_t)(b * SS + qw + quad * 4)) * DD + h * 64 + l16];
#pragma unroll
    for (int r = 0; r < 4; ++r)
#pragma unroll
        for (int dt = 0; dt < 4; ++dt)
            ob[(size_t)r * DD + dt * 16] = f2bf(oacc[dt][r] * inv[r]);
}

// ---------------------------------------------------------------------------
extern "C" void kernel_launch(void* const* d_in, const int* in_sizes, int n_in,
                              void* d_out, int out_size, void* d_ws, size_t ws_size,
                              hipStream_t stream)
{
    const float* X  = (const float*)d_in[0];
    const float* Wq = (const float*)d_in[1];
    const float* Wk = (const float*)d_in[2];
    const float* Wv = (const float*)d_in[3];
    const float* Wo = (const float*)d_in[4];
    float* Out = (float*)d_out;

    // d_ws (needs 2*XSZ u16 = 12.6MB, verified since R15):
    //   [0,XSZ)    Qb (Q bf16, attn output in-place)
    //   [XSZ,2XSZ) Kb (K bf16)
    // d_out (2*XSZ u16): [0,XSZ) = V^T bf16 (dead before gemm_of's fp32
    //   output overwrites); [XSZ,+3WSZ) = bf16 Wq,Wk,Wv (dead after QKV GEMM).
    unsigned short* Qb  = (unsigned short*)d_ws;
    unsigned short* Kb  = Qb + XSZ;
    unsigned short* Vtb = (unsigned short*)d_out;
    unsigned short* Wqb = Vtb + XSZ;

    dim3 blk(256);

    cvt_w3<<<1728, blk, 0, stream>>>(Wq, Wk, Wv, Wqb);

    dim3 g1(DD / 64, MM / 64);                      // 768 blocks: fused QKV
    gemm_qkv64<<<g1, blk, 0, stream>>>(X, Wqb, Wqb + WSZ, Wqb + 2 * WSZ,
                                       Qb, Kb, Vtb);

    dim3 g2(HH, BB, SS / 64);                       // 768 blocks: LDS-staged attn
    attn_ls<<<g2, blk, 0, stream>>>(Qb, Kb, Vtb, Qb);

    dim3 g3(DD / 64, MM / 64);                      // 768 blocks: out projection
    gemm_of<<<g3, blk, 0, stream>>>(Qb, Wo, Out);
}

// Round 15
// 151.245 us; speedup vs baseline: 1.0501x; 1.0501x over previous
//
#include <hip/hip_runtime.h>
#include <stdint.h>

// Problem constants (fixed by the reference)
#define BB   2
#define SS   2048
#define DD   768
#define HH   12
#define MM   (BB*SS)          // 4096 rows in all GEMMs
#define XSZ  (MM*DD)          // 3,145,728
#define WSZ  (DD*DD)          //   589,824

typedef __bf16 v8bf __attribute__((ext_vector_type(8)));   // 8 bf16 = 4 VGPRs (MFMA A/B frag)
typedef float  v4f  __attribute__((ext_vector_type(4)));   // MFMA C/D frag (16x16)

__device__ inline v4f mfma16(v8bf a, v8bf b, v4f c) {
    return __builtin_amdgcn_mfma_f32_16x16x32_bf16(a, b, c, 0, 0, 0);
}

// float -> bf16 bits, round-to-nearest-even
__device__ inline unsigned short f2bf(float f) {
    union { float f; uint32_t u; } v; v.f = f;
    return (unsigned short)((v.u + 0x7FFFu + ((v.u >> 16) & 1u)) >> 16);
}

// 8 contiguous fp32 -> 8 bf16 packed into 16 bytes (VGPR staging path)
__device__ inline uint4 cvt8(const float* __restrict__ p) {
    uint4 out;
    unsigned short* s = (unsigned short*)&out;
#pragma unroll
    for (int j = 0; j < 8; ++j) s[j] = f2bf(p[j]);
    return out;
}

// Async 16B global->LDS copy (gfx950). LDS dest is wave-uniform base + lane*16B.
__device__ __forceinline__ void gld_lds16(const unsigned short* g, unsigned short* l) {
    __builtin_amdgcn_global_load_lds(
        (const __attribute__((address_space(1))) void*)g,
        (__attribute__((address_space(3))) void*)l, 16, 0, 0);
}

// ---------------------------------------------------------------------------
// R16-verified: fp32 -> bf16 for Wq,Wk,Wv into d_out's second half (3*WSZ
// elems = 1728 blocks x 256 thr x 4 elems exactly). ~10.6MB => ~2.5us.
// ---------------------------------------------------------------------------
__global__ __launch_bounds__(256) void cvt_w3(
    const float* __restrict__ Wq, const float* __restrict__ Wk,
    const float* __restrict__ Wv, unsigned short* __restrict__ dst)
{
    long i4 = ((long)blockIdx.x * 256 + threadIdx.x) * 4;
    int t = (int)(i4 / WSZ);
    long off = i4 - (long)t * WSZ;
    const float* s = (t == 0) ? Wq : (t == 1) ? Wk : Wv;
    float4 v = *(const float4*)(s + off);
    ushort4 o;
    o.x = f2bf(v.x); o.y = f2bf(v.y); o.z = f2bf(v.z); o.w = f2bf(v.w);
    *(ushort4*)(dst + (size_t)t * WSZ + off) = o;
}

// ---------------------------------------------------------------------------
// R26-verified QKV (R16 structure, B-issues first -- measured equal to R16
// within noise): X-tile staged once (cvt8, XOR-swizzled ds_write), 3 bf16
// weight tiles async via global_load_lds (source pre-swizzled). 24 MFMA/wave
// per BK=64 step. Grid (12,64)=768 = 3/CU, XCD-chunked.
// ---------------------------------------------------------------------------
__global__ __launch_bounds__(256) void gemm_qkv64(
    const float* __restrict__ X,
    const unsigned short* __restrict__ Wq,
    const unsigned short* __restrict__ Wk,
    const unsigned short* __restrict__ Wv,
    unsigned short* __restrict__ Qo,
    unsigned short* __restrict__ Ko,
    unsigned short* __restrict__ Vo)
{
    __shared__ __align__(16) unsigned short As[64 * 64];
    __shared__ __align__(16) unsigned short Bs[3][64 * 64];

    const int flat = (int)(blockIdx.y * gridDim.x + blockIdx.x);
    const int sw   = (flat & 7) * 96 + (flat >> 3);
    const int m0   = (sw / 12) * 64;
    const int n0   = (sw % 12) * 64;

    const int tid  = threadIdx.x;
    const int wave = tid >> 6, lane = tid & 63;
    const int quad = lane >> 4, l16 = lane & 15;
    const int waveM = (wave >> 1) * 32, waveN = (wave & 1) * 32;

    const int rA  = tid >> 2;
    const int cA  = (tid & 3) * 16;
    const int rxA = (rA & 7) << 4;

    const int rB  = wave * 8 + (lane >> 3);
    const int cB  = ((lane & 7) ^ (lane >> 3)) * 8;
    const int swz = (l16 & 7) << 4;

    v4f acc[3][2][2] = {};

    const float* ap0 = X + (size_t)(m0 + rA) * DD + cA;
    const unsigned short* w0 = Wq + (size_t)(n0 + rB) * DD + cB;
    const unsigned short* w1 = Wk + (size_t)(n0 + rB) * DD + cB;
    const unsigned short* w2 = Wv + (size_t)(n0 + rB) * DD + cB;

    for (int kt = 0; kt < DD; kt += 64) {
        __syncthreads();
        // B first: 6 async issues fly while the A chain stalls on its loads.
        gld_lds16(w0 + kt,           &Bs[0][wave * 512]);
        gld_lds16(w0 + kt + 32 * DD, &Bs[0][2048 + wave * 512]);
        gld_lds16(w1 + kt,           &Bs[1][wave * 512]);
        gld_lds16(w1 + kt + 32 * DD, &Bs[1][2048 + wave * 512]);
        gld_lds16(w2 + kt,           &Bs[2][wave * 512]);
        gld_lds16(w2 + kt + 32 * DD, &Bs[2][2048 + wave * 512]);
        // A: 16 fp32 -> bf16, two swizzled ds_write_b128
        *(uint4*)((char*)As + rA * 128 + ((cA * 2)      ^ rxA)) = cvt8(ap0 + kt);
        *(uint4*)((char*)As + rA * 128 + ((cA * 2 + 16) ^ rxA)) = cvt8(ap0 + kt + 8);
        __syncthreads();

        v8bf af[2][2];
#pragma unroll
        for (int mi = 0; mi < 2; ++mi) {
            const char* arow = (const char*)As + (size_t)(waveM + mi * 16 + l16) * 128;
#pragma unroll
            for (int kf = 0; kf < 2; ++kf)
                af[mi][kf] = *(const v8bf*)(arow + ((kf * 64 + quad * 16) ^ swz));
        }
#pragma unroll
        for (int z = 0; z < 3; ++z) {
            v8bf bfr[2][2];
#pragma unroll
            for (int ni = 0; ni < 2; ++ni) {
                const char* brow = (const char*)&Bs[z][0] + (size_t)(waveN + ni * 16 + l16) * 128;
#pragma unroll
                for (int kf = 0; kf < 2; ++kf)
                    bfr[ni][kf] = *(const v8bf*)(brow + ((kf * 64 + quad * 16) ^ swz));
            }
#pragma unroll
            for (int mi = 0; mi < 2; ++mi)
#pragma unroll
                for (int ni = 0; ni < 2; ++ni) {
                    acc[z][mi][ni] = mfma16(af[mi][0], bfr[ni][0], acc[z][mi][ni]);
                    acc[z][mi][ni] = mfma16(af[mi][1], bfr[ni][1], acc[z][mi][ni]);
                }
        }
    }

    // Epilogue: C/D layout col=l16, row=quad*4+r (verified formula).
#pragma unroll
    for (int mi = 0; mi < 2; ++mi)
#pragma unroll
        for (int ni = 0; ni < 2; ++ni)
#pragma unroll
            for (int r = 0; r < 4; ++r) {
                const int row = m0 + waveM + mi * 16 + quad * 4 + r;
                const int col = n0 + waveN + ni * 16 + l16;
                Qo[(size_t)row * DD + col] = f2bf(acc[0][mi][ni][r]);
                Ko[(size_t)row * DD + col] = f2bf(acc[1][mi][ni][r]);
                const int b = row >> 11, s = row & 2047;
                const int h = col >> 6,  dk = col & 63;
                Vo[(((size_t)(b * HH + h)) * 64 + dk) * SS + s] = f2bf(acc[2][mi][ni][r]);
            }
}

// ---------------------------------------------------------------------------
// R21-verified out-projection: 64x64, BK=64, double-buffered T3 2-phase.
// A bf16 async; W = Wo fp32 via cvt8 swizzled ds_write. Grid (12,64)=768.
// ---------------------------------------------------------------------------
__global__ __launch_bounds__(256) void gemm_of(
    const unsigned short* __restrict__ A,
    const float* __restrict__ W,
    float* __restrict__ C)
{
    __shared__ __align__(16) unsigned short As[2][64 * 64];
    __shared__ __align__(16) unsigned short Bs[2][64 * 64];

    const int flat = (int)(blockIdx.y * gridDim.x + blockIdx.x);  // gx=12
    const int sw   = (flat & 7) * 96 + (flat >> 3);
    const int m0   = (sw / 12) * 64;
    const int n0   = (sw % 12) * 64;

    const int tid  = threadIdx.x;
    const int wave = tid >> 6, lane = tid & 63;
    const int quad = lane >> 4, l16 = lane & 15;
    const int waveM = (wave >> 1) * 32, waveN = (wave & 1) * 32;

    const int rB  = wave * 8 + (lane >> 3);
    const int cB  = ((lane & 7) ^ (lane >> 3)) * 8;
    const int rW  = tid >> 2;
    const int cW  = (tid & 3) * 16;
    const int rxW = (rW & 7) << 4;
    const int swz = (l16 & 7) << 4;

    const unsigned short* a0 = A + (size_t)(m0 + rB) * DD + cB;
    const float*          b0 = W + (size_t)(n0 + rW) * DD + cW;

    v4f acc[2][2] = {};

    gld_lds16(a0,           &As[0][wave * 512]);
    gld_lds16(a0 + 32 * DD, &As[0][2048 + wave * 512]);
    *(uint4*)((char*)&Bs[0][0] + rW * 128 + ((cW * 2)      ^ rxW)) = cvt8(b0);
    *(uint4*)((char*)&Bs[0][0] + rW * 128 + ((cW * 2 + 16) ^ rxW)) = cvt8(b0 + 8);
    __syncthreads();

    int cur = 0;
    for (int kt = 0; kt < DD; kt += 64) {
        if (kt + 64 < DD) {
            gld_lds16(a0 + kt + 64,           &As[cur ^ 1][wave * 512]);
            gld_lds16(a0 + kt + 64 + 32 * DD, &As[cur ^ 1][2048 + wave * 512]);
            *(uint4*)((char*)&Bs[cur ^ 1][0] + rW * 128 + ((cW * 2)      ^ rxW)) = cvt8(b0 + kt + 64);
            *(uint4*)((char*)&Bs[cur ^ 1][0] + rW * 128 + ((cW * 2 + 16) ^ rxW)) = cvt8(b0 + kt + 64 + 8);
        }
#pragma unroll
        for (int kf = 0; kf < 2; ++kf) {
            v8bf af[2], bfr[2];
#pragma unroll
            for (int i = 0; i < 2; ++i) {
                af[i]  = *(const v8bf*)((const char*)&As[cur][0] +
                          (size_t)(waveM + i * 16 + l16) * 128 + ((kf * 64 + quad * 16) ^ swz));
                bfr[i] = *(const v8bf*)((const char*)&Bs[cur][0] +
                          (size_t)(waveN + i * 16 + l16) * 128 + ((kf * 64 + quad * 16) ^ swz));
            }
#pragma unroll
            for (int mi = 0; mi < 2; ++mi)
#pragma unroll
                for (int ni = 0; ni < 2; ++ni)
                    acc[mi][ni] = mfma16(af[mi], bfr[ni], acc[mi][ni]);
        }
        __syncthreads();
        cur ^= 1;
    }

#pragma unroll
    for (int mi = 0; mi < 2; ++mi)
#pragma unroll
        for (int ni = 0; ni < 2; ++ni)
#pragma unroll
            for (int r = 0; r < 4; ++r) {
                const int row = m0 + waveM + mi * 16 + quad * 4 + r;
                const int col = n0 + waveN + ni * 16 + l16;
                C[(size_t)row * DD + col] = acc[mi][ni][r];
            }
}

// ---------------------------------------------------------------------------
// R27-verified attention (session best, 153.0us total): R15 structure with
// SWAPPED QK^T operands (mfma(K,Q)): lane holds col=l16 = ITS q-row, rows =
// keys. P write is 4 x ds_write_b64 (vs 16 scalar), diag mask lane-uniform,
// row-sum a single scalar + 2 shfl_xor. R28's T15 lagged-PV variant measured
// neutral-on-attn / negative-on-total (bank conflicts 3x) -> reverted.
// ---------------------------------------------------------------------------
__global__ __launch_bounds__(256, 3) void attn_ls(
    const unsigned short* Q,                 // (B,S,D) bf16 (aliases O)
    const unsigned short* __restrict__ Kg,   // (B,S,D) bf16
    const unsigned short* __restrict__ Vt,   // (B,H,64,S) bf16 transposed
    unsigned short* O)                       // (B,S,D) bf16
{
    const int h = blockIdx.x, b = blockIdx.y;
    const int qs = (SS / 64 - 1 - (int)blockIdx.z) * 64;   // LPT: heavy first
    const int tid  = threadIdx.x;
    const int wave = tid >> 6, lane = tid & 63;
    const int quad = lane >> 4, l16 = lane & 15;
    const int qw = qs + wave * 16;           // this wave's private q rows
    const float scale = 0.125f;              // 1/sqrt(64)

    __shared__ __align__(16) unsigned short Ks[2][4096];   // 2 x 64x64 bf16, swizzled
    __shared__ __align__(16) unsigned short Vs[2][4096];   // 2 x 64x64 bf16, swizzled
    __shared__ __align__(16) unsigned short Ps[4][16 * 72];// per-wave P buffer

    // Q frags for this wave's 16 rows (read before any O write: in-place safe)
    v8bf qf0, qf1;
    {
        const unsigned short* qp = &Q[((size_t)(b * SS + qw + l16)) * DD + h * 64];
        qf0 = *(const v8bf*)(qp + quad * 8);
        qf1 = *(const v8bf*)(qp + 32 + quad * 8);
    }

    const int NT = qs / 64 + 1;              // causal k-tiles, SAME for all 4 waves
    const char* kgb = (const char*)&Kg[(size_t)(b * SS) * DD + h * 64];
    const char* vgb = (const char*)&Vt[((size_t)(b * HH + h) * 64) * SS];

    const int rA = wave * 8 + (lane >> 3);               // rows rA and rA+32
    const int oA = ((lane & 7) * 16) ^ ((rA & 7) << 4);  // swizzled in-row byte
    const int swz = (l16 & 7) << 4;                      // read-side XOR

    v4f oacc[4] = {};
    float l_sum = 0.0f;                      // q-row l16, this quad's partial
    unsigned short* pw = &Ps[wave][0];
    const int qrow = qw + l16;               // lane-uniform mask row

    // Prologue: stage tile 0 into buffer 0
    gld_lds16((const unsigned short*)(kgb + (size_t)rA        * (DD * 2) + oA), &Ks[0][wave * 512]);
    gld_lds16((const unsigned short*)(kgb + (size_t)(rA + 32) * (DD * 2) + oA), &Ks[0][2048 + wave * 512]);
    gld_lds16((const unsigned short*)(vgb + (size_t)rA        * (SS * 2) + oA), &Vs[0][wave * 512]);
    gld_lds16((const unsigned short*)(vgb + (size_t)(rA + 32) * (SS * 2) + oA), &Vs[0][2048 + wave * 512]);
    __syncthreads();   // drains vmcnt: tile 0 resident

    for (int kt = 0; kt < NT; ++kt) {
        const int cur = kt & 1;
        const int kb  = kt * 64;

        // Async-stage NEXT tile into the other buffer
        if (kt + 1 < NT) {
            const size_t kb2 = (size_t)(kb + 64);
            gld_lds16((const unsigned short*)(kgb + (kb2 + rA)      * (DD * 2) + oA), &Ks[cur ^ 1][wave * 512]);
            gld_lds16((const unsigned short*)(kgb + (kb2 + rA + 32) * (DD * 2) + oA), &Ks[cur ^ 1][2048 + wave * 512]);
            gld_lds16((const unsigned short*)(vgb + (size_t)rA        * (SS * 2) + kb2 * 2 + oA), &Vs[cur ^ 1][wave * 512]);
            gld_lds16((const unsigned short*)(vgb + (size_t)(rA + 32) * (SS * 2) + kb2 * 2 + oA), &Vs[cur ^ 1][2048 + wave * 512]);
        }

        const char* ksb = (const char*)&Ks[cur][0];
        const char* vsb = (const char*)&Vs[cur][0];

        // K frags from swizzled LDS: row = nk*16+l16, cols half*32 + quad*8..
        v8bf kf0[4], kf1[4];
#pragma unroll
        for (int nk = 0; nk < 4; ++nk) {
            const char* krow = ksb + (size_t)(nk * 16 + l16) * 128;
            kf0[nk] = *(const v8bf*)(krow + ((quad * 16) ^ swz));
            kf1[nk] = *(const v8bf*)(krow + ((64 + quad * 16) ^ swz));
        }

        // S^T = K Q^T (swapped operands): lane = q-row l16; rows = keys.
        v4f sacc[4] = {};
#pragma unroll
        for (int nk = 0; nk < 4; ++nk) {
            sacc[nk] = mfma16(kf0[nk], qf0, sacc[nk]);
            sacc[nk] = mfma16(kf1[nk], qf1, sacc[nk]);
        }

        // fixed-base softmax: p = exp(s/8); mask only on the diagonal tile.
        // pv[nk][r] = P[qrow l16][key kb + nk*16 + quad*4 + r].
        const bool diag = (kt == NT - 1);
        float pv[4][4];
#pragma unroll
        for (int nk = 0; nk < 4; ++nk)
#pragma unroll
            for (int r = 0; r < 4; ++r) {
                float p = __expf(sacc[nk][r] * scale);
                if (diag) {
                    int key = kb + nk * 16 + quad * 4 + r;
                    if (key > qrow) p = 0.0f;
                }
                pv[nk][r] = p;
                l_sum += p;
            }

        // V frags (issued before the P round-trip so latency overlaps it)
        v8bf vf[2][4];
#pragma unroll
        for (int kc = 0; kc < 2; ++kc)
#pragma unroll
            for (int dt = 0; dt < 4; ++dt) {
                const char* vr = vsb + (size_t)(dt * 16 + l16) * 128;
                vf[kc][dt] = *(const v8bf*)(vr + ((kc * 64 + quad * 16) ^ swz));
            }

        // P chunks -> per-wave LDS [qrow][key] (stride 72): 4 x ds_write_b64.
        // Content identical to R15's 16 scalar writes -> read side unchanged.
#pragma unroll
        for (int nk = 0; nk < 4; ++nk) {
            uint2 c;
            c.x = (uint32_t)f2bf(pv[nk][0]) | ((uint32_t)f2bf(pv[nk][1]) << 16);
            c.y = (uint32_t)f2bf(pv[nk][2]) | ((uint32_t)f2bf(pv[nk][3]) << 16);
            *(uint2*)(&pw[l16 * 72 + nk * 16 + quad * 4]) = c;
        }
        __asm__ volatile("" ::: "memory");

        v8bf pa0 = *(const v8bf*)(&pw[l16 * 72 + quad * 8]);
        v8bf pa1 = *(const v8bf*)(&pw[l16 * 72 + 32 + quad * 8]);
#pragma unroll
        for (int dt = 0; dt < 4; ++dt) oacc[dt] = mfma16(pa0, vf[0][dt], oacc[dt]);
#pragma unroll
        for (int dt = 0; dt < 4; ++dt) oacc[dt] = mfma16(pa1, vf[1][dt], oacc[dt]);

        // One barrier per tile: reads of buf[cur] done + buf[cur^1] resident.
        __syncthreads();
    }

    // l_sum is the quad-partial for q-row l16: reduce across the 4 quads,
    // then broadcast the sums this lane's 4 output rows need.
    l_sum += __shfl_xor(l_sum, 16, 64);
    l_sum += __shfl_xor(l_sum, 32, 64);
    float inv[4];
#pragma unroll
    for (int r = 0; r < 4; ++r)
        inv[r] = 1.0f / __shfl(l_sum, quad * 4 + r, 64);

    // Direct per-wave store: lane holds O[qw+quad*4+r][dt*16+l16] (C layout).
    unsigned short* ob = &O[((size_t)(b * SS + qw + quad * 4)) * DD + h * 64 + l16];
#pragma unroll
    for (int r = 0; r < 4; ++r)
#pragma unroll
        for (int dt = 0; dt < 4; ++dt)
            ob[(size_t)r * DD + dt * 16] = f2bf(oacc[dt][r] * inv[r]);
}

// ---------------------------------------------------------------------------
extern "C" void kernel_launch(void* const* d_in, const int* in_sizes, int n_in,
                              void* d_out, int out_size, void* d_ws, size_t ws_size,
                              hipStream_t stream)
{
    const float* X  = (const float*)d_in[0];
    const float* Wq = (const float*)d_in[1];
    const float* Wk = (const float*)d_in[2];
    const float* Wv = (const float*)d_in[3];
    const float* Wo = (const float*)d_in[4];
    float* Out = (float*)d_out;

    // d_ws (needs 2*XSZ u16 = 12.6MB, verified since R15):
    //   [0,XSZ)    Qb (Q bf16, attn output in-place)
    //   [XSZ,2XSZ) Kb (K bf16)
    // d_out (2*XSZ u16): [0,XSZ) = V^T bf16 (dead before gemm_of's fp32
    //   output overwrites); [XSZ,+3WSZ) = bf16 Wq,Wk,Wv (dead after QKV GEMM).
    unsigned short* Qb  = (unsigned short*)d_ws;
    unsigned short* Kb  = Qb + XSZ;
    unsigned short* Vtb = (unsigned short*)d_out;
    unsigned short* Wqb = Vtb + XSZ;

    dim3 blk(256);

    cvt_w3<<<1728, blk, 0, stream>>>(Wq, Wk, Wv, Wqb);

    dim3 g1(DD / 64, MM / 64);                      // 768 blocks: fused QKV
    gemm_qkv64<<<g1, blk, 0, stream>>>(X, Wqb, Wqb + WSZ, Wqb + 2 * WSZ,
                                       Qb, Kb, Vtb);

    dim3 g2(HH, BB, SS / 64);                       // 768 blocks: LDS-staged attn
    attn_ls<<<g2, blk, 0, stream>>>(Qb, Kb, Vtb, Qb);

    dim3 g3(DD / 64, MM / 64);                      // 768 blocks: out projection
    gemm_of<<<g3, blk, 0, stream>>>(Qb, Wo, Out);
}